// Round 4
// baseline (385.942 us; speedup 1.0000x reference)
//
#include <hip/hip_runtime.h>

// ============================================================================
// ContDecoder on MI355X — round 4: 32x32x16 MFMA + register reuse (MS=2,NG=2).
//
// Model from round 3: MfmaUtil was pinned at ~18% because every MFMA consumed
// one LDS fragment + one global fragment (operand delivery ~2KB/cyc demand vs
// ~190 B/cyc supply). Fix: 32x32x16 (2x FLOP per fragment byte) and reuse each
// A-frag across NG=2 n-tiles, each B-frag across MS=2 m-tiles -> 4x less
// traffic per FLOP on both pipes. 4 waves/block (unit count for L1 = 4),
// MPTS=64, 1 block/CU, latency hidden by in-wave ILP (4 indep acc chains).
//
// LDS per point (bf16 elems): [hA 0..544 | hB 544..800 | xin 800..848],
// SROW=856 (856/8=107 odd -> uniform 16B-quad bank spread for b128).
// Chain: xin(37p48) ->W0-> hA(516p544) ->W1-> hB(256) ->W2-> hA(128)
//   ->W3-> hB(64) ->W4-> hA(32) ->W5-> hB(16p32) ->W6-> out(2).
// Pad neurons get zero weights + zero bias -> exact zeros, so concat/ragged
// dims are free and stale LDS regions are never read.
// ============================================================================

#define NTH     256
#define NWAVES  4
#define MPTS    64              // 2 m-tiles of 32 points
#define SROW    856
#define HA_OFF  0
#define HB_OFF  544
#define XIN_OFF 800
#define NPOINTS (8 * 16384)
#define GRIDX   (NPOINTS / MPTS)     // 2048 blocks
#define LDSBYTES (MPTS * SROW * 2)   // 109568

typedef short          short8 __attribute__((ext_vector_type(8)));
typedef float          f32x16 __attribute__((ext_vector_type(16)));
typedef unsigned short u16;
typedef unsigned int   u32;

__device__ __forceinline__ u32 f2bf(float f) {
    u32 u = __builtin_bit_cast(u32, f);
    u += 0x7fffu + ((u >> 16) & 1u);        // round-to-nearest-even
    return u >> 16;
}

// ---------------------------------------------------------------------------
// Packed-weight geometry: 1KB fragments of 512 bf16. Fragment (l, nt, s):
// lane holds W[k = s*16 + (lane>>5)*8 + j][n = nt*32 + (lane&31)], j=0..7.
//   l : KHS(k16-steps hidden)  KS  NT   frag_base
//   0 :  0                      3  17      0       (xin-only, K=48)
//   1 : 34                     37   8     51
//   2 : 16                     19   4    347
//   3 :  8                     11   2    423
//   4 :  4                      7   1    445
//   5 :  2                      5   1    452
//   6 :  1                      1   1    457     total 458 frags = 458 KB
// ---------------------------------------------------------------------------
__constant__ int pk_base[8] = {0, 51, 347, 423, 445, 452, 457, 458};
__constant__ int pk_ks[7]   = {3, 37, 19, 11, 7, 5, 1};
__constant__ int pk_khs[7]  = {0, 34, 16, 8, 4, 2, 1};
__constant__ int pk_kact[7] = {0, 516, 256, 128, 64, 32, 16};
__constant__ int pk_nact[7] = {516, 256, 128, 64, 32, 16, 2};

struct WPtrs { const float* W[7]; };

// One thread = one (fragment, lane) 16B piece: writes coalesce perfectly.
__global__ void pack_weights(WPtrs wp, u16* __restrict__ out)
{
    const int gid = blockIdx.x * blockDim.x + threadIdx.x;
    if (gid >= 458 * 64) return;
    const int f    = gid >> 6;
    const int lane = gid & 63;
    int l = 0;
    while (l < 6 && f >= pk_base[l + 1]) ++l;
    const int r    = f - pk_base[l];
    const int ks   = pk_ks[l];
    const int nt   = r / ks;
    const int s    = r % ks;
    const int n    = nt * 32 + (lane & 31);
    const int k0   = s * 16 + (lane >> 5) * 8;
    const int khid = pk_khs[l] * 16;
    const int kact = pk_kact[l];
    const int nact = pk_nact[l];
    const float* W = wp.W[l];

    union { short8 v; u16 e[8]; } frag;
#pragma unroll
    for (int j = 0; j < 8; ++j) {
        const int k = k0 + j;
        float v = 0.0f;
        if (n < nact) {
            if (k < khid) {
                if (k < kact) v = W[k * nact + n];
            } else if (l < 6) {
                const int xr = k - khid;
                if (xr < 37) v = W[(kact + xr) * nact + n];
            }
        }
        frag.e[j] = (u16)f2bf(v);
    }
    *(short8*)(out + (size_t)gid * 8) = frag.v;
}

// ---------------------------------------------------------------------------
// One MLP layer. Unit = (NG n-tiles) x (both m-tiles). Units strided over 4
// waves. Per k-step: 2 A ds_read_b128 + NG B global loads + 2*NG MFMA.
// A layout: A[m=lane&31][k=(lane>>5)*8+j]; B: W[k][n=lane&31] (packed);
// D: col(n)=lane&31, row(pt)=(reg&3)+8*(reg>>2)+4*(lane>>5)  [m74/m101].
// Epilogue: DPP xor-1 pairs neurons (n,n+1) -> even lanes ds_write_b32.
// ---------------------------------------------------------------------------
template<int KHS, int HSEG, int OSEG, int NT, int NG, int NACT, int LBASE,
         bool XIN, bool RELU, bool GOUT>
__device__ __forceinline__ void mlayer(const u16* __restrict__ wpack,
                                       const float* __restrict__ bias,
                                       u16* __restrict__ s_act,
                                       float* __restrict__ gout, int p0,
                                       int wave, int lane)
{
    constexpr int KS   = KHS + (XIN ? 3 : 0);
    constexpr int NGRP = (NT + NG - 1) / NG;
    const int nl   = lane & 31;
    const int half = lane >> 5;
    const u16* arow0 = s_act + nl * SROW + half * 8;
    const u16* arow1 = s_act + (32 + nl) * SROW + half * 8;

    for (int g = wave; g < NGRP; g += NWAVES) {
        const int n0 = g * NG;
        f32x16 acc[NG][2];
#pragma unroll
        for (int t = 0; t < NG; ++t) {
            acc[t][0] = (f32x16)(0.0f);
            acc[t][1] = (f32x16)(0.0f);
        }
#pragma unroll
        for (int s = 0; s < KS; ++s) {
            const int ab = (s < KHS) ? (HSEG + s * 16)
                                     : (XIN_OFF + (s - KHS) * 16);
            const short8 a0 = *(const short8*)(arow0 + ab);
            const short8 a1 = *(const short8*)(arow1 + ab);
#pragma unroll
            for (int t = 0; t < NG; ++t) {
                const int nt = n0 + t;
                if ((NT % NG) && nt >= NT) break;
                const short8 b = *(const short8*)(wpack +
                        ((size_t)(LBASE + nt * KS + s) << 9) + lane * 8);
                acc[t][0] = __builtin_amdgcn_mfma_f32_32x32x16_bf16(a0, b, acc[t][0], 0, 0, 0);
                acc[t][1] = __builtin_amdgcn_mfma_f32_32x32x16_bf16(a1, b, acc[t][1], 0, 0, 0);
            }
        }

#pragma unroll
        for (int t = 0; t < NG; ++t) {
            const int nt = n0 + t;
            if ((NT % NG) && nt >= NT) break;
            const int n = nt * 32 + nl;
            const float bv = (n < NACT) ? bias[n] : 0.0f;
#pragma unroll
            for (int m = 0; m < 2; ++m) {
#pragma unroll
                for (int q = 0; q < 4; ++q) {
#pragma unroll
                    for (int r = 0; r < 4; ++r) {
                        float v = acc[t][m][q * 4 + r] + bv;
                        if (RELU) v = fmaxf(v, 0.0f);
                        const int pt = m * 32 + q * 8 + half * 4 + r;
                        if (GOUT) {
                            if (nl < 2) gout[(size_t)(p0 + pt) * 2 + nl] = v;
                        } else {
                            // neighbor-lane value via DPP quad_perm(1,0,3,2)
                            const int vi = __builtin_bit_cast(int, v);
                            const int oi = __builtin_amdgcn_update_dpp(
                                               0, vi, 0xB1, 0xF, 0xF, true);
                            const float ov = __builtin_bit_cast(float, oi);
                            const u32 dw = f2bf(v) | (f2bf(ov) << 16);
                            if (!(nl & 1))   // even neuron lanes write the pair
                                *(u32*)(s_act + pt * SROW + OSEG + n) = dw;
                        }
                    }
                }
            }
        }
    }
}

struct MainParams {
    const float* lr;     // [B,2,64,64]
    const float* ctx;    // [B,32,64,64]
    const float* eps;    // [B,64,64]
    const float* coord;  // [B,N,2]
    const float* Bb[7];  // biases (fp32)
    const u16*   wpack;  // packed bf16 weights in d_ws
    float*       out;    // [B,N,2]
};

__global__ __launch_bounds__(NTH, 1)
void cont_decoder_mfma(MainParams p)
{
    extern __shared__ u16 s_act[];         // MPTS*SROW bf16 = 109568 B
    __shared__ int   s_x0[MPTS], s_y0[MPTS];
    __shared__ float s_wx[MPTS], s_wy[MPTS];

    const int tid  = threadIdx.x;
    const int wave = tid >> 6;
    const int lane = tid & 63;
    const int p0   = blockIdx.x * MPTS;
    const int b    = p0 >> 14;             // 16384 points per batch

    // ---- zero xin pad cols [37..48) ----
    for (int i = tid; i < MPTS * 11; i += NTH) {
        const int pt = i / 11, c = 37 + i % 11;
        s_act[pt * SROW + XIN_OFF + c] = 0;
    }

    // ---- bilinear params + coord features ----
    if (tid < MPTS) {
        const int pt = p0 + tid;
        const float cx = p.coord[2 * pt];
        const float cy = p.coord[2 * pt + 1];
        const float gx = (cx + 1.0f) * 32.0f - 0.5f;   // align_corners=False
        const float gy = (cy + 1.0f) * 32.0f - 0.5f;
        const float fx0 = floorf(gx), fy0 = floorf(gy);
        s_x0[tid] = (int)fx0;
        s_y0[tid] = (int)fy0;
        s_wx[tid] = gx - fx0;
        s_wy[tid] = gy - fy0;
        s_act[tid * SROW + XIN_OFF + 32] = (u16)f2bf(cx);
        s_act[tid * SROW + XIN_OFF + 33] = (u16)f2bf(cy);
    }
    __syncthreads();

    // ---- sample 35 channels/point (ref swaps spatial axes: val = g[b,c,x,y]) ----
    for (int idx = tid; idx < MPTS * 35; idx += NTH) {
        const int t = idx / 35;
        const int c = idx % 35;
        const float* base;
        int col;
        if (c < 32)      { base = p.ctx + (size_t)(b * 32 + c) * 4096;       col = c; }
        else if (c < 34) { base = p.lr  + (size_t)(b * 2 + (c - 32)) * 4096; col = 34 + (c - 32); }
        else             { base = p.eps + (size_t)b * 4096;                   col = 36; }

        const int   x0 = s_x0[t], y0 = s_y0[t];
        const float wx = s_wx[t], wy = s_wy[t];
        const int x1 = x0 + 1, y1 = y0 + 1;
        const bool xv0 = (x0 >= 0) & (x0 < 64);
        const bool xv1 = (x1 >= 0) & (x1 < 64);
        const bool yv0 = (y0 >= 0) & (y0 < 64);
        const bool yv1 = (y1 >= 0) & (y1 < 64);
        const int xc0 = min(max(x0, 0), 63), xc1 = min(max(x1, 0), 63);
        const int yc0 = min(max(y0, 0), 63), yc1 = min(max(y1, 0), 63);

        const float w00 = (1.0f - wx) * (1.0f - wy) * ((xv0 && yv0) ? 1.0f : 0.0f);
        const float w10 = wx * (1.0f - wy)          * ((xv1 && yv0) ? 1.0f : 0.0f);
        const float w01 = (1.0f - wx) * wy          * ((xv0 && yv1) ? 1.0f : 0.0f);
        const float w11 = wx * wy                   * ((xv1 && yv1) ? 1.0f : 0.0f);

        const float val = w00 * base[xc0 * 64 + yc0]
                        + w10 * base[xc1 * 64 + yc0]
                        + w01 * base[xc0 * 64 + yc1]
                        + w11 * base[xc1 * 64 + yc1];
        s_act[t * SROW + XIN_OFF + col] = (u16)f2bf(val);
    }
    __syncthreads();

    // ---- MLP ----
    //       KHS  HSEG    OSEG    NT  NG NACT LBASE  XIN    RELU   GOUT
    mlayer<  0,  HA_OFF, HA_OFF, 17, 2, 516, 0,     true,  true,  false>(p.wpack, p.Bb[0], s_act, nullptr, p0, wave, lane);
    __syncthreads();
    mlayer< 34,  HA_OFF, HB_OFF,  8, 2, 256, 51,    true,  true,  false>(p.wpack, p.Bb[1], s_act, nullptr, p0, wave, lane);
    __syncthreads();
    mlayer< 16,  HB_OFF, HA_OFF,  4, 2, 128, 347,   true,  true,  false>(p.wpack, p.Bb[2], s_act, nullptr, p0, wave, lane);
    __syncthreads();
    mlayer<  8,  HA_OFF, HB_OFF,  2, 1,  64, 423,   true,  true,  false>(p.wpack, p.Bb[3], s_act, nullptr, p0, wave, lane);
    __syncthreads();
    mlayer<  4,  HB_OFF, HA_OFF,  1, 1,  32, 445,   true,  true,  false>(p.wpack, p.Bb[4], s_act, nullptr, p0, wave, lane);
    __syncthreads();
    mlayer<  2,  HA_OFF, HB_OFF,  1, 1,  16, 452,   true,  true,  false>(p.wpack, p.Bb[5], s_act, nullptr, p0, wave, lane);
    __syncthreads();
    mlayer<  1,  HB_OFF, 0,       1, 1,   2, 457,   false, false, true >(p.wpack, p.Bb[6], s_act, p.out,   p0, wave, lane);
}

extern "C" void kernel_launch(void* const* d_in, const int* in_sizes, int n_in,
                              void* d_out, int out_size, void* d_ws, size_t ws_size,
                              hipStream_t stream)
{
    WPtrs wp;
    for (int l = 0; l < 7; ++l) wp.W[l] = (const float*)d_in[4 + 2 * l];

    MainParams p;
    p.lr    = (const float*)d_in[0];
    p.ctx   = (const float*)d_in[1];
    p.eps   = (const float*)d_in[2];
    p.coord = (const float*)d_in[3];
    for (int l = 0; l < 7; ++l) p.Bb[l] = (const float*)d_in[5 + 2 * l];
    p.wpack = (const u16*)d_ws;
    p.out   = (float*)d_out;

    // Opt in to >64 KB dynamic LDS (idempotent; capture-safe).
    hipFuncSetAttribute((const void*)cont_decoder_mfma,
                        hipFuncAttributeMaxDynamicSharedMemorySize, LDSBYTES);

    hipLaunchKernelGGL(pack_weights, dim3((458 * 64 + 255) / 256), dim3(256), 0, stream, wp, (u16*)d_ws);
    hipLaunchKernelGGL(cont_decoder_mfma, dim3(GRIDX), dim3(NTH), LDSBYTES, stream, p);
}

// Round 5
// 276.272 us; speedup vs baseline: 1.3970x; 1.3970x over previous
//
#include <hip/hip_runtime.h>

// ============================================================================
// ContDecoder on MI355X — round 5: 32x32x16 MFMA, reuse + TLP restored.
//
// Round-4 lesson: 4 waves/CU cannot hide L2 B-load latency (311 us, MfmaUtil
// 8%). Round 5 keeps the low-operand-traffic structure (32x32 MFMA, B shared
// across m-tiles, A shared across n-tiles) but runs 8 waves (512 thr),
// MPTS=64, 1 block/CU; per-layer (NG, MS) picked so units >= 8 on the layers
// that dominate (L1: 8 units x 37 k-steps).
//
// LDS per point (bf16 elems): [hA 0..544 | hB 544..800 | xin 800..848],
// SROW=856. Chain: xin(37p48) ->W0-> hA(516p544) ->W1-> hB(256) ->W2->
// hA(128) ->W3-> hB(64) ->W4-> hA(32) ->W5-> hB(16p32) ->W6-> out(2).
// Pad neurons: zero weights + zero bias -> exact zeros (concat & stale-LDS
// safe). Epilogue: DPP lane-pair -> ds_write_b32, conflict-free.
// ============================================================================

#define NTH     512
#define NWAVES  8
#define MPTS    64              // 2 m-tiles of 32 points
#define SROW    856
#define HA_OFF  0
#define HB_OFF  544
#define XIN_OFF 800
#define NPOINTS (8 * 16384)
#define GRIDX   (NPOINTS / MPTS)     // 2048 blocks
#define LDSBYTES (MPTS * SROW * 2)   // 109568

typedef short          short8 __attribute__((ext_vector_type(8)));
typedef float          f32x16 __attribute__((ext_vector_type(16)));
typedef unsigned short u16;
typedef unsigned int   u32;

__device__ __forceinline__ u32 f2bf(float f) {
    u32 u = __builtin_bit_cast(u32, f);
    u += 0x7fffu + ((u >> 16) & 1u);        // round-to-nearest-even
    return u >> 16;
}

// ---------------------------------------------------------------------------
// Packed-weight geometry: 1KB fragments of 512 bf16. Fragment (l, nt, s):
// lane holds W[k = s*16 + (lane>>5)*8 + j][n = nt*32 + (lane&31)], j=0..7.
//   l : KHS  KS  NT   frag_base
//   0 :  0    3  17      0       (xin-only, K=48)
//   1 : 34   37   8     51
//   2 : 16   19   4    347
//   3 :  8   11   2    423
//   4 :  4    7   1    445
//   5 :  2    5   1    452
//   6 :  1    1   1    457     total 458 frags = 458 KB in d_ws
// ---------------------------------------------------------------------------
__constant__ int pk_base[8] = {0, 51, 347, 423, 445, 452, 457, 458};
__constant__ int pk_ks[7]   = {3, 37, 19, 11, 7, 5, 1};
__constant__ int pk_khs[7]  = {0, 34, 16, 8, 4, 2, 1};
__constant__ int pk_kact[7] = {0, 516, 256, 128, 64, 32, 16};
__constant__ int pk_nact[7] = {516, 256, 128, 64, 32, 16, 2};

struct WPtrs { const float* W[7]; };

// One thread = one (fragment, lane) 16B piece: writes coalesce perfectly.
__global__ void pack_weights(WPtrs wp, u16* __restrict__ out)
{
    const int gid = blockIdx.x * blockDim.x + threadIdx.x;
    if (gid >= 458 * 64) return;
    const int f    = gid >> 6;
    const int lane = gid & 63;
    int l = 0;
    while (l < 6 && f >= pk_base[l + 1]) ++l;
    const int r    = f - pk_base[l];
    const int ks   = pk_ks[l];
    const int nt   = r / ks;
    const int s    = r % ks;
    const int n    = nt * 32 + (lane & 31);
    const int k0   = s * 16 + (lane >> 5) * 8;
    const int khid = pk_khs[l] * 16;
    const int kact = pk_kact[l];
    const int nact = pk_nact[l];
    const float* W = wp.W[l];

    union { short8 v; u16 e[8]; } frag;
#pragma unroll
    for (int j = 0; j < 8; ++j) {
        const int k = k0 + j;
        float v = 0.0f;
        if (n < nact) {
            if (k < khid) {
                if (k < kact) v = W[k * nact + n];
            } else if (l < 6) {
                const int xr = k - khid;
                if (xr < 37) v = W[(kact + xr) * nact + n];
            }
        }
        frag.e[j] = (u16)f2bf(v);
    }
    *(short8*)(out + (size_t)gid * 8) = frag.v;
}

// ---------------------------------------------------------------------------
// One MLP layer. Unit = (NG n-tiles) x (MS m-tiles); units strided over 8
// waves. Per k-step: MS A ds_read_b128 + NG B global loads + NG*MS MFMA.
// A layout: A[m=lane&31][k=(lane>>5)*8+j]; B: W[k][n=lane&31] (packed);
// D: col(n)=lane&31, row(pt)=(reg&3)+8*(reg>>2)+4*(lane>>5)  [m74/m101].
// Epilogue: DPP quad_perm pairs neurons (n,n+1) -> even lanes ds_write_b32.
// ---------------------------------------------------------------------------
template<int KHS, int HSEG, int OSEG, int NT, int NG, int MS, int NACT,
         int LBASE, bool XIN, bool RELU, bool GOUT>
__device__ __forceinline__ void mlayer(const u16* __restrict__ wpack,
                                       const float* __restrict__ bias,
                                       u16* __restrict__ s_act,
                                       float* __restrict__ gout, int p0,
                                       int wave, int lane)
{
    constexpr int KS    = KHS + (XIN ? 3 : 0);
    constexpr int NGRP  = (NT + NG - 1) / NG;
    constexpr int MGRP  = 2 / MS;            // 2 m-tiles of 32 points
    constexpr int UNITS = NGRP * MGRP;
    const int nl   = lane & 31;
    const int half = lane >> 5;

    for (int u = wave; u < UNITS; u += NWAVES) {
        const int gn = u % NGRP;
        const int gm = u / NGRP;
        const int n0 = gn * NG;
        const int m0 = gm * MS;

        const u16* arow[MS];
#pragma unroll
        for (int m = 0; m < MS; ++m)
            arow[m] = s_act + ((m0 + m) * 32 + nl) * SROW + half * 8;

        f32x16 acc[NG][MS];
#pragma unroll
        for (int t = 0; t < NG; ++t)
#pragma unroll
            for (int m = 0; m < MS; ++m)
                acc[t][m] = (f32x16)(0.0f);

#pragma unroll
        for (int s = 0; s < KS; ++s) {
            const int ab = (s < KHS) ? (HSEG + s * 16)
                                     : (XIN_OFF + (s - KHS) * 16);
            short8 a[MS];
#pragma unroll
            for (int m = 0; m < MS; ++m)
                a[m] = *(const short8*)(arow[m] + ab);
#pragma unroll
            for (int t = 0; t < NG; ++t) {
                const int nt = n0 + t;
                if ((NT % NG) && nt >= NT) break;
                const short8 b = *(const short8*)(wpack +
                        ((size_t)(LBASE + nt * KS + s) << 9) + lane * 8);
#pragma unroll
                for (int m = 0; m < MS; ++m)
                    acc[t][m] = __builtin_amdgcn_mfma_f32_32x32x16_bf16(a[m], b, acc[t][m], 0, 0, 0);
            }
        }

#pragma unroll
        for (int t = 0; t < NG; ++t) {
            const int nt = n0 + t;
            if ((NT % NG) && nt >= NT) break;
            const int n = nt * 32 + nl;
            const float bv = (n < NACT) ? bias[n] : 0.0f;
#pragma unroll
            for (int m = 0; m < MS; ++m) {
#pragma unroll
                for (int q = 0; q < 4; ++q) {
#pragma unroll
                    for (int r = 0; r < 4; ++r) {
                        float v = acc[t][m][q * 4 + r] + bv;
                        if (RELU) v = fmaxf(v, 0.0f);
                        const int pt = (m0 + m) * 32 + q * 8 + half * 4 + r;
                        if (GOUT) {
                            if (nl < 2) gout[(size_t)(p0 + pt) * 2 + nl] = v;
                        } else {
                            // neighbor-lane value via DPP quad_perm(1,0,3,2)
                            const int vi = __builtin_bit_cast(int, v);
                            const int oi = __builtin_amdgcn_update_dpp(
                                               0, vi, 0xB1, 0xF, 0xF, true);
                            const float ov = __builtin_bit_cast(float, oi);
                            const u32 dw = f2bf(v) | (f2bf(ov) << 16);
                            if (!(nl & 1))   // even neuron lanes write the pair
                                *(u32*)(s_act + pt * SROW + OSEG + n) = dw;
                        }
                    }
                }
            }
        }
    }
}

struct MainParams {
    const float* lr;     // [B,2,64,64]
    const float* ctx;    // [B,32,64,64]
    const float* eps;    // [B,64,64]
    const float* coord;  // [B,N,2]
    const float* Bb[7];  // biases (fp32)
    const u16*   wpack;  // packed bf16 weights in d_ws
    float*       out;    // [B,N,2]
};

__global__ __launch_bounds__(NTH, 1)
void cont_decoder_mfma(MainParams p)
{
    extern __shared__ u16 s_act[];         // MPTS*SROW bf16 = 109568 B
    __shared__ int   s_x0[MPTS], s_y0[MPTS];
    __shared__ float s_wx[MPTS], s_wy[MPTS];

    const int tid  = threadIdx.x;
    const int wave = tid >> 6;
    const int lane = tid & 63;
    const int p0   = blockIdx.x * MPTS;
    const int b    = p0 >> 14;             // 16384 points per batch

    // ---- zero xin pad cols [37..48) ----
    for (int i = tid; i < MPTS * 11; i += NTH) {
        const int pt = i / 11, c = 37 + i % 11;
        s_act[pt * SROW + XIN_OFF + c] = 0;
    }

    // ---- bilinear params + coord features ----
    if (tid < MPTS) {
        const int pt = p0 + tid;
        const float cx = p.coord[2 * pt];
        const float cy = p.coord[2 * pt + 1];
        const float gx = (cx + 1.0f) * 32.0f - 0.5f;   // align_corners=False
        const float gy = (cy + 1.0f) * 32.0f - 0.5f;
        const float fx0 = floorf(gx), fy0 = floorf(gy);
        s_x0[tid] = (int)fx0;
        s_y0[tid] = (int)fy0;
        s_wx[tid] = gx - fx0;
        s_wy[tid] = gy - fy0;
        s_act[tid * SROW + XIN_OFF + 32] = (u16)f2bf(cx);
        s_act[tid * SROW + XIN_OFF + 33] = (u16)f2bf(cy);
    }
    __syncthreads();

    // ---- sample 35 channels/point (ref swaps spatial axes: val = g[b,c,x,y]) ----
    for (int idx = tid; idx < MPTS * 35; idx += NTH) {
        const int t = idx / 35;
        const int c = idx % 35;
        const float* base;
        int col;
        if (c < 32)      { base = p.ctx + (size_t)(b * 32 + c) * 4096;       col = c; }
        else if (c < 34) { base = p.lr  + (size_t)(b * 2 + (c - 32)) * 4096; col = 34 + (c - 32); }
        else             { base = p.eps + (size_t)b * 4096;                   col = 36; }

        const int   x0 = s_x0[t], y0 = s_y0[t];
        const float wx = s_wx[t], wy = s_wy[t];
        const int x1 = x0 + 1, y1 = y0 + 1;
        const bool xv0 = (x0 >= 0) & (x0 < 64);
        const bool xv1 = (x1 >= 0) & (x1 < 64);
        const bool yv0 = (y0 >= 0) & (y0 < 64);
        const bool yv1 = (y1 >= 0) & (y1 < 64);
        const int xc0 = min(max(x0, 0), 63), xc1 = min(max(x1, 0), 63);
        const int yc0 = min(max(y0, 0), 63), yc1 = min(max(y1, 0), 63);

        const float w00 = (1.0f - wx) * (1.0f - wy) * ((xv0 && yv0) ? 1.0f : 0.0f);
        const float w10 = wx * (1.0f - wy)          * ((xv1 && yv0) ? 1.0f : 0.0f);
        const float w01 = (1.0f - wx) * wy          * ((xv0 && yv1) ? 1.0f : 0.0f);
        const float w11 = wx * wy                   * ((xv1 && yv1) ? 1.0f : 0.0f);

        const float val = w00 * base[xc0 * 64 + yc0]
                        + w10 * base[xc1 * 64 + yc0]
                        + w01 * base[xc0 * 64 + yc1]
                        + w11 * base[xc1 * 64 + yc1];
        s_act[t * SROW + XIN_OFF + col] = (u16)f2bf(val);
    }
    __syncthreads();

    // ---- MLP ----
    //       KHS  HSEG    OSEG    NT  NG MS NACT LBASE  XIN    RELU   GOUT
    mlayer<  0,  HA_OFF, HA_OFF, 17, 2, 2, 516, 0,     true,  true,  false>(p.wpack, p.Bb[0], s_act, nullptr, p0, wave, lane);
    __syncthreads();
    mlayer< 34,  HA_OFF, HB_OFF,  8, 1, 2, 256, 51,    true,  true,  false>(p.wpack, p.Bb[1], s_act, nullptr, p0, wave, lane);
    __syncthreads();
    mlayer< 16,  HB_OFF, HA_OFF,  4, 1, 1, 128, 347,   true,  true,  false>(p.wpack, p.Bb[2], s_act, nullptr, p0, wave, lane);
    __syncthreads();
    mlayer<  8,  HA_OFF, HB_OFF,  2, 1, 1,  64, 423,   true,  true,  false>(p.wpack, p.Bb[3], s_act, nullptr, p0, wave, lane);
    __syncthreads();
    mlayer<  4,  HB_OFF, HA_OFF,  1, 1, 1,  32, 445,   true,  true,  false>(p.wpack, p.Bb[4], s_act, nullptr, p0, wave, lane);
    __syncthreads();
    mlayer<  2,  HA_OFF, HB_OFF,  1, 1, 1,  16, 452,   true,  true,  false>(p.wpack, p.Bb[5], s_act, nullptr, p0, wave, lane);
    __syncthreads();
    mlayer<  1,  HB_OFF, 0,       1, 1, 1,   2, 457,   false, false, true >(p.wpack, p.Bb[6], s_act, p.out,   p0, wave, lane);
}

extern "C" void kernel_launch(void* const* d_in, const int* in_sizes, int n_in,
                              void* d_out, int out_size, void* d_ws, size_t ws_size,
                              hipStream_t stream)
{
    WPtrs wp;
    for (int l = 0; l < 7; ++l) wp.W[l] = (const float*)d_in[4 + 2 * l];

    MainParams p;
    p.lr    = (const float*)d_in[0];
    p.ctx   = (const float*)d_in[1];
    p.eps   = (const float*)d_in[2];
    p.coord = (const float*)d_in[3];
    for (int l = 0; l < 7; ++l) p.Bb[l] = (const float*)d_in[5 + 2 * l];
    p.wpack = (const u16*)d_ws;
    p.out   = (float*)d_out;

    // Opt in to >64 KB dynamic LDS (idempotent; capture-safe).
    hipFuncSetAttribute((const void*)cont_decoder_mfma,
                        hipFuncAttributeMaxDynamicSharedMemorySize, LDSBYTES);

    hipLaunchKernelGGL(pack_weights, dim3((458 * 64 + 255) / 256), dim3(256), 0, stream, wp, (u16*)d_ws);
    hipLaunchKernelGGL(cont_decoder_mfma, dim3(GRIDX), dim3(NTH), LDSBYTES, stream, p);
}